// Round 6
// baseline (268.353 us; speedup 1.0000x reference)
//
#include <hip/hip_runtime.h>
#include <math.h>

// Problem constants
#define Hc 384
#define Wc 512
#define Bc 4
#define NP 12
#define HWc (Hc * Wc)        // 196608
#define Pc (Bc * HWc)        // 786432
#define MAX_FLOW_C 443.40500673763256f   // sqrt(384*512)
#define LOG2_C 0.69314718055994530942f   // ln(2)
#define L2E_C  1.44269504088896340736f   // log2(e)

#define NCH 4    // step chunks (blocks per pixel-group)
#define NSPC 3   // steps per chunk (NCH*NSPC == NP)

typedef float vf4 __attribute__((ext_vector_type(4)));

__device__ __forceinline__ float fexp2(float x) {
#if __has_builtin(__builtin_amdgcn_exp2f)
    return __builtin_amdgcn_exp2f(x);
#else
    return exp2f(x);
#endif
}
__device__ __forceinline__ float flog2(float x) {
#if __has_builtin(__builtin_amdgcn_logf)
    return __builtin_amdgcn_logf(x);   // v_log_f32 = log2
#else
    return log2f(x);
#endif
}

// logsumexp in base-2 units: lse22(a,b) = log2(2^a + 2^b)
__device__ __forceinline__ float lse22(float a, float b) {
    float m = fmaxf(a, b);
    float d = fminf(a, b) - m;   // <= 0
    return m + flog2(1.0f + fexp2(d));
}

// acc layout: [0..11] per-step sum of nf' (base-2 units), [12..23] per-step
// count, [24] mask1 count.  Finalize multiplies sums by ln(2).
__global__ __launch_bounds__(256) void loss_main(
    const float* __restrict__ fp,     // (12,4,2,H,W)
    const float* __restrict__ ip,     // (12,4,4,H,W)
    const float* __restrict__ gt,     // (4,2,H,W)
    const float* __restrict__ valid,  // (4,1,H,W)
    float* __restrict__ acc) {

    const int chunk = blockIdx.x & (NCH - 1);
    const int gb    = blockIdx.x >> 2;
    const int g  = gb * 256 + threadIdx.x;          // float4-group id, exact cover
    const int b  = g / (HWc / 4);
    const int hw = (g % (HWc / 4)) * 4;
    const int n0 = chunk * NSPC;

    // ---- issue ALL loads up-front: 3 (gt/valid) + 15 (streams) in flight ----
    const vf4 gx4 = *(const vf4*)(gt + ((size_t)b * 2 + 0) * HWc + hw);
    const vf4 gy4 = *(const vf4*)(gt + ((size_t)b * 2 + 1) * HWc + hw);
    const vf4 vv4 = *(const vf4*)(valid + (size_t)b * HWc + hw);

    vf4 fx4[NSPC], fy4[NSPC], a04[NSPC], a14[NSPC], lb4[NSPC];
#pragma unroll
    for (int k = 0; k < NSPC; ++k) {
        const int n = n0 + k;
        const float* fbase = fp + ((size_t)(n * Bc + b) * 2) * HWc + hw;
        const float* ibase = ip + ((size_t)(n * Bc + b) * 4) * HWc + hw;
        fx4[k] = *(const vf4*)(fbase);
        fy4[k] = *(const vf4*)(fbase + HWc);
        a04[k] = *(const vf4*)(ibase);
        a14[k] = *(const vf4*)(ibase + HWc);
        lb4[k] = *(const vf4*)(ibase + 2 * (size_t)HWc);
        // info channel 3 never read: clip(x, 0, 0) == 0 identically.
    }

    float gxa[4] = {gx4.x, gx4.y, gx4.z, gx4.w};
    float gya[4] = {gy4.x, gy4.y, gy4.z, gy4.w};
    float vva[4] = {vv4.x, vv4.y, vv4.z, vv4.w};

    bool  m1[4];
    float mcnt = 0.0f;
#pragma unroll
    for (int j = 0; j < 4; ++j) {
        float mag = sqrtf(gxa[j] * gxa[j] + gya[j] * gya[j]);
        m1[j] = (mag < MAX_FLOW_C) && (vva[j] != 0.0f);
        mcnt += m1[j] ? 1.0f : 0.0f;
    }

    float s[NSPC];
    float c[NSPC];
#pragma unroll
    for (int k = 0; k < NSPC; ++k) { s[k] = 0.0f; c[k] = 0.0f; }

#pragma unroll
    for (int k = 0; k < NSPC; ++k) {
        float fxa[4] = {fx4[k].x, fx4[k].y, fx4[k].z, fx4[k].w};
        float fya[4] = {fy4[k].x, fy4[k].y, fy4[k].z, fy4[k].w};
        float a0a[4] = {a04[k].x, a04[k].y, a04[k].z, a04[k].w};
        float a1a[4] = {a14[k].x, a14[k].y, a14[k].z, a14[k].w};
        float lba[4] = {lb4[k].x, lb4[k].y, lb4[k].z, lb4[k].w};

#pragma unroll
        for (int j = 0; j < 4; ++j) {
            // Base-2 units: X' = X*log2(e); nf = ln2 * nf'.
            // Residuals scaled too: D = |gt-flow| * log2(e).
            float LB  = fminf(fmaxf(lba[j], 0.0f), 10.0f) * L2E_C;
            float e2  = fexp2(-LB);             // exp(-lb0), unscaled
            float A0  = a0a[j] * L2E_C;
            float A1  = a1a[j] * L2E_C;
            float lsa = lse22(A0, A1);
            float t10 = A0 - 1.0f - LB;
            float t11 = A1 - 1.0f;              // lb1 == 0
            float D0  = fabsf(gxa[j] - fxa[j]) * L2E_C;
            float D1  = fabsf(gya[j] - fya[j]) * L2E_C;

            float nf0 = lsa - lse22(t10 - D0 * e2, t11 - D0);
            float nf1 = lsa - lse22(t10 - D1 * e2, t11 - D1);

            bool ok0 = m1[j] && isfinite(nf0);
            bool ok1 = m1[j] && isfinite(nf1);
            s[k] += ok0 ? nf0 : 0.0f;
            c[k] += ok0 ? 1.0f : 0.0f;
            s[k] += ok1 ? nf1 : 0.0f;
            c[k] += ok1 ? 1.0f : 0.0f;
        }
    }

    // ---- reduction: wave shuffle -> LDS -> atomics ----
#pragma unroll
    for (int k = 0; k < NSPC; ++k) {
        for (int off = 32; off > 0; off >>= 1) {
            s[k] += __shfl_down(s[k], off);
            c[k] += __shfl_down(c[k], off);
        }
    }
    for (int off = 32; off > 0; off >>= 1) mcnt += __shfl_down(mcnt, off);

    __shared__ float red[4][2 * NSPC + 1];
    const int lane = threadIdx.x & 63;
    const int wid  = threadIdx.x >> 6;
    if (lane == 0) {
#pragma unroll
        for (int k = 0; k < NSPC; ++k) {
            red[wid][k]        = s[k];
            red[wid][NSPC + k] = c[k];
        }
        red[wid][2 * NSPC] = mcnt;
    }
    __syncthreads();
    if (threadIdx.x < 2 * NSPC + 1) {
        float v = red[0][threadIdx.x] + red[1][threadIdx.x] +
                  red[2][threadIdx.x] + red[3][threadIdx.x];
        int idx;
        if (threadIdx.x < NSPC)           idx = n0 + threadIdx.x;             // sums
        else if (threadIdx.x < 2 * NSPC)  idx = 12 + n0 + threadIdx.x - NSPC; // counts
        else                              idx = 24;                           // mcnt
        if (idx != 24 || chunk == 0)      // mcnt counted once, not per chunk
            atomicAdd(&acc[idx], v);
    }
}

__global__ void loss_final(const float* __restrict__ acc, float* __restrict__ out) {
    if (blockIdx.x == 0 && threadIdx.x == 0) {
        float loss = 0.0f;
#pragma unroll
        for (int n = 0; n < NP; ++n)
            loss += LOG2_C * acc[n] / fmaxf(acc[12 + n], 1.0f);
        float mean_mask = acc[24] / (float)Pc;
        out[0] = (mean_mask < 0.25f) ? 0.0f : loss;
    }
}

extern "C" void kernel_launch(void* const* d_in, const int* in_sizes, int n_in,
                              void* d_out, int out_size, void* d_ws, size_t ws_size,
                              hipStream_t stream) {
    const float* fp    = (const float*)d_in[0];
    const float* ip    = (const float*)d_in[1];
    const float* gt    = (const float*)d_in[2];
    const float* valid = (const float*)d_in[3];
    float* acc = (float*)d_ws;

    (void)hipMemsetAsync(acc, 0, 25 * sizeof(float), stream);
    loss_main<<<(Pc / 4 / 256) * NCH, 256, 0, stream>>>(fp, ip, gt, valid, acc);
    loss_final<<<1, 64, 0, stream>>>(acc, (float*)d_out);
}

// Round 7
// 253.193 us; speedup vs baseline: 1.0599x; 1.0599x over previous
//
#include <hip/hip_runtime.h>
#include <math.h>

// Problem constants
#define Hc 384
#define Wc 512
#define Bc 4
#define NP 12
#define HWc (Hc * Wc)        // 196608
#define Pc (Bc * HWc)        // 786432
#define MAX_FLOW_C 443.40500673763256f   // sqrt(384*512)
#define LOG2_C 0.69314718055994530942f   // ln(2)
#define L2E_C  1.44269504088896340736f   // log2(e)

#define NCH 2    // step chunks (blocks per pixel-group)
#define NSPC 6   // steps per chunk (NCH*NSPC == NP)
#define NBG 768  // pixel-group blocks (Pc/4/256)
#define NQ 25    // 12 sums + 12 counts + mask-count

typedef float vf4 __attribute__((ext_vector_type(4)));

__device__ __forceinline__ float fexp2(float x) {
#if __has_builtin(__builtin_amdgcn_exp2f)
    return __builtin_amdgcn_exp2f(x);
#else
    return exp2f(x);
#endif
}
__device__ __forceinline__ float flog2(float x) {
#if __has_builtin(__builtin_amdgcn_logf)
    return __builtin_amdgcn_logf(x);   // v_log_f32 = log2
#else
    return log2f(x);
#endif
}

// logsumexp in base-2 units: lse22(a,b) = log2(2^a + 2^b)
__device__ __forceinline__ float lse22(float a, float b) {
    float m = fmaxf(a, b);
    float d = fminf(a, b) - m;   // <= 0
    return m + flog2(1.0f + fexp2(d));
}

// Streaming one-touch loads (L3 is evicted by the harness's ws poison fill
// anyway; nt keeps the stream out of L2 so gt/valid lines survive).
__device__ __forceinline__ vf4 ldnt4(const float* p) {
    return __builtin_nontemporal_load((const vf4*)p);
}

// Stage 1: per-block partials, NO atomics (same-address atomic chains were
// the suspected serializer).  part[q * NBG + gb], q in [0, NQ).
__global__ __launch_bounds__(256) void loss_part(
    const float* __restrict__ fp,     // (12,4,2,H,W)
    const float* __restrict__ ip,     // (12,4,4,H,W)
    const float* __restrict__ gt,     // (4,2,H,W)
    const float* __restrict__ valid,  // (4,1,H,W)
    float* __restrict__ part) {

    const int chunk = blockIdx.x & (NCH - 1);
    const int gb    = blockIdx.x >> 1;
    const int g  = gb * 256 + threadIdx.x;          // float4-group id, exact cover
    const int b  = g / (HWc / 4);
    const int hw = (g % (HWc / 4)) * 4;
    const int n0 = chunk * NSPC;

    const vf4 gx4 = *(const vf4*)(gt + ((size_t)b * 2 + 0) * HWc + hw);
    const vf4 gy4 = *(const vf4*)(gt + ((size_t)b * 2 + 1) * HWc + hw);
    const vf4 vv4 = *(const vf4*)(valid + (size_t)b * HWc + hw);

    float gxa[4] = {gx4.x, gx4.y, gx4.z, gx4.w};
    float gya[4] = {gy4.x, gy4.y, gy4.z, gy4.w};
    float vva[4] = {vv4.x, vv4.y, vv4.z, vv4.w};

    bool  m1[4];
    float mcnt = 0.0f;
#pragma unroll
    for (int j = 0; j < 4; ++j) {
        float mag = sqrtf(gxa[j] * gxa[j] + gya[j] * gya[j]);
        m1[j] = (mag < MAX_FLOW_C) && (vva[j] != 0.0f);
        mcnt += m1[j] ? 1.0f : 0.0f;
    }

    float s[NSPC];
    float c[NSPC];
#pragma unroll
    for (int k = 0; k < NSPC; ++k) { s[k] = 0.0f; c[k] = 0.0f; }

#pragma unroll
    for (int k = 0; k < NSPC; ++k) {
        const int n = n0 + k;
        const float* fbase = fp + ((size_t)(n * Bc + b) * 2) * HWc + hw;
        const float* ibase = ip + ((size_t)(n * Bc + b) * 4) * HWc + hw;

        const vf4 fx4 = ldnt4(fbase);
        const vf4 fy4 = ldnt4(fbase + HWc);
        const vf4 a04 = ldnt4(ibase);
        const vf4 a14 = ldnt4(ibase + HWc);
        const vf4 lb4 = ldnt4(ibase + 2 * (size_t)HWc);
        // info channel 3 never read: clip(x, 0, 0) == 0 identically.

        float fxa[4] = {fx4.x, fx4.y, fx4.z, fx4.w};
        float fya[4] = {fy4.x, fy4.y, fy4.z, fy4.w};
        float a0a[4] = {a04.x, a04.y, a04.z, a04.w};
        float a1a[4] = {a14.x, a14.y, a14.z, a14.w};
        float lba[4] = {lb4.x, lb4.y, lb4.z, lb4.w};

#pragma unroll
        for (int j = 0; j < 4; ++j) {
            // Base-2 units: X' = X*log2(e); nf = ln2 * nf'.
            float LB  = fminf(fmaxf(lba[j], 0.0f), 10.0f) * L2E_C;
            float e2  = fexp2(-LB);             // exp(-lb0), unscaled
            float A0  = a0a[j] * L2E_C;
            float A1  = a1a[j] * L2E_C;
            float lsa = lse22(A0, A1);
            float t10 = A0 - 1.0f - LB;
            float t11 = A1 - 1.0f;              // lb1 == 0
            float D0  = fabsf(gxa[j] - fxa[j]) * L2E_C;
            float D1  = fabsf(gya[j] - fya[j]) * L2E_C;

            float nf0 = lsa - lse22(t10 - D0 * e2, t11 - D0);
            float nf1 = lsa - lse22(t10 - D1 * e2, t11 - D1);

            bool ok0 = m1[j] && isfinite(nf0);
            bool ok1 = m1[j] && isfinite(nf1);
            s[k] += ok0 ? nf0 : 0.0f;
            c[k] += ok0 ? 1.0f : 0.0f;
            s[k] += ok1 ? nf1 : 0.0f;
            c[k] += ok1 ? 1.0f : 0.0f;
        }
    }

    // ---- reduction: wave shuffle -> LDS -> plain stores (no atomics) ----
#pragma unroll
    for (int k = 0; k < NSPC; ++k) {
        for (int off = 32; off > 0; off >>= 1) {
            s[k] += __shfl_down(s[k], off);
            c[k] += __shfl_down(c[k], off);
        }
    }
    for (int off = 32; off > 0; off >>= 1) mcnt += __shfl_down(mcnt, off);

    __shared__ float red[4][2 * NSPC + 1];
    const int lane = threadIdx.x & 63;
    const int wid  = threadIdx.x >> 6;
    if (lane == 0) {
#pragma unroll
        for (int k = 0; k < NSPC; ++k) {
            red[wid][k]        = s[k];
            red[wid][NSPC + k] = c[k];
        }
        red[wid][2 * NSPC] = mcnt;
    }
    __syncthreads();
    if (threadIdx.x < 2 * NSPC + 1) {
        float v = red[0][threadIdx.x] + red[1][threadIdx.x] +
                  red[2][threadIdx.x] + red[3][threadIdx.x];
        int q;
        if (threadIdx.x < NSPC)           q = n0 + threadIdx.x;             // sums 0..11
        else if (threadIdx.x < 2 * NSPC)  q = 12 + n0 + threadIdx.x - NSPC; // counts 12..23
        else                              q = 24;                           // mcnt
        if (q != 24 || chunk == 0)        // q=24 written by chunk-0 blocks only
            part[(size_t)q * NBG + gb] = v;
    }
    // Every part[] slot is written every launch -> no zero-init needed.
}

// Stage 2: one block per quantity, reduce 768 partials -> acc2[q].
__global__ __launch_bounds__(256) void loss_reduce(
    const float* __restrict__ part, float* __restrict__ acc2) {
    const int q = blockIdx.x;
    const float* p = part + (size_t)q * NBG;
    float v = 0.0f;
    for (int i = threadIdx.x; i < NBG; i += 256) v += p[i];
    for (int off = 32; off > 0; off >>= 1) v += __shfl_down(v, off);
    __shared__ float r[4];
    if ((threadIdx.x & 63) == 0) r[threadIdx.x >> 6] = v;
    __syncthreads();
    if (threadIdx.x == 0) acc2[q] = r[0] + r[1] + r[2] + r[3];
}

// Stage 3: assemble scalar loss.
__global__ void loss_final(const float* __restrict__ acc2, float* __restrict__ out) {
    if (blockIdx.x == 0 && threadIdx.x == 0) {
        float loss = 0.0f;
#pragma unroll
        for (int n = 0; n < NP; ++n)
            loss += LOG2_C * acc2[n] / fmaxf(acc2[12 + n], 1.0f);
        float mean_mask = acc2[24] / (float)Pc;
        out[0] = (mean_mask < 0.25f) ? 0.0f : loss;
    }
}

extern "C" void kernel_launch(void* const* d_in, const int* in_sizes, int n_in,
                              void* d_out, int out_size, void* d_ws, size_t ws_size,
                              hipStream_t stream) {
    const float* fp    = (const float*)d_in[0];
    const float* ip    = (const float*)d_in[1];
    const float* gt    = (const float*)d_in[2];
    const float* valid = (const float*)d_in[3];
    float* part = (float*)d_ws;                    // NQ * NBG floats
    float* acc2 = part + (size_t)NQ * NBG;         // NQ floats

    loss_part<<<NBG * NCH, 256, 0, stream>>>(fp, ip, gt, valid, part);
    loss_reduce<<<NQ, 256, 0, stream>>>(part, acc2);
    loss_final<<<1, 64, 0, stream>>>(acc2, (float*)d_out);
}